// Round 5
// baseline (156.071 us; speedup 1.0000x reference)
//
#include <hip/hip_runtime.h>
#include <hip/hip_bf16.h>
#include <math.h>

#define DD 64
#define NPB 2048          // nodes per batch (N)
#define RTOT 65536        // total node rows B*N
#define W1S 136           // padded stride for [64][128] weight tile
#define W2S 72            // padded stride for [64][64]-ish tiles
#define HBS 136           // h(0:64) + msgs(64:128) combined tile stride
#define TROWS 80          // 64 output rows + 16-row halo

typedef __bf16 bf16;
typedef bf16 bf16x8 __attribute__((ext_vector_type(8)));
typedef float f32x4 __attribute__((ext_vector_type(4)));

#define COMPILER_FENCE() asm volatile("" ::: "memory")

__device__ __forceinline__ f32x4 mfma16(bf16x8 a, bf16x8 b, f32x4 c) {
  return __builtin_amdgcn_mfma_f32_16x16x32_bf16(a, b, c, 0, 0, 0);
}

__device__ __forceinline__ float gelu_exact(float x) {
  return 0.5f * x * (1.0f + erff(x * 0.70710678118654752f));
}

__device__ __forceinline__ bf16x8 ld8(const bf16* p) {
  return *reinterpret_cast<const bf16x8*>(p);
}

__device__ __forceinline__ bf16x8 zero8() {
  bf16x8 z = {(bf16)0.f, (bf16)0.f, (bf16)0.f, (bf16)0.f,
              (bf16)0.f, (bf16)0.f, (bf16)0.f, (bf16)0.f};
  return z;
}

// ---- prep: all weights -> bf16, transposed, into ws scratch ----
// Wsc: [0:8192) wm1t[n][k], [8192:16384) wu1t, [16384:20480) wm2t,
//      [20480:24576) wu2t, [24576:40960) wrt[v][k]
__global__ void __launch_bounds__(256) k_prep(const float* __restrict__ wm1,
                                              const float* __restrict__ wm2,
                                              const float* __restrict__ wu1,
                                              const float* __restrict__ wu2,
                                              const float* __restrict__ wr,
                                              bf16* __restrict__ Wsc) {
  int gid = blockIdx.x * 256 + threadIdx.x;   // 160 * 256 = 40960
  if (gid < 8192) {
    int n = gid >> 7, k = gid & 127;
    Wsc[gid] = (bf16)wm1[k * 64 + n];
  } else if (gid < 16384) {
    int j = gid - 8192, n = j >> 7, k = j & 127;
    Wsc[gid] = (bf16)wu1[k * 64 + n];
  } else if (gid < 20480) {
    int j = gid - 16384, n = j >> 6, k = j & 63;
    Wsc[gid] = (bf16)wm2[k * 64 + n];
  } else if (gid < 24576) {
    int j = gid - 20480, n = j >> 6, k = j & 63;
    Wsc[gid] = (bf16)wu2[k * 64 + n];
  } else {
    int j = gid - 24576, v = j >> 6, k = j & 63;
    Wsc[gid] = (bf16)wr[k * 256 + v];
  }
}

// ---------------- fused: embed -> 3 rounds -> readout ----------------
// 320 threads = 5 waves; tile rows 0..79 <-> global rows rb-16+tr (rb=blk*64).
// Wave wv owns tile rows [16wv,16wv+16). Rows rb-3..rb+63 are exact; deeper
// halo rows are garbage-but-finite and provably never feed stored outputs
// (batch-start rows use the left=0 mask, and only 3 halo levels are consumed).
__global__ void __launch_bounds__(320) k_fused(const int* __restrict__ x,
                                               const float* __restrict__ emb,
                                               const bf16* __restrict__ Wsc,
                                               const float* __restrict__ bm1,
                                               const float* __restrict__ bm2,
                                               const float* __restrict__ bu1,
                                               const float* __restrict__ bu2,
                                               const float* __restrict__ lng,
                                               const float* __restrict__ lnb,
                                               const float* __restrict__ br,
                                               float* __restrict__ out) {
  // arena: Hs[80*72] @0 (11520B) | W1[64*136] @11520 (17408B) | Hb[80*136]
  // @28928 (21760B). Readout Wt[128*72] (18432B) overlays Hs+W1 (dead then).
  __shared__ __align__(16) char arena[50688];
  bf16* Hs = (bf16*)arena;
  bf16* W1 = (bf16*)(arena + 11520);
  bf16* Hb = (bf16*)(arena + 28928);
  bf16* Wt = (bf16*)arena;

  const bf16* wm1t = Wsc;
  const bf16* wu1t = Wsc + 8192;
  const bf16* wm2t = Wsc + 16384;
  const bf16* wu2t = Wsc + 20480;
  const bf16* wrt  = Wsc + 24576;

  const int tid = threadIdx.x;
  const int lane = tid & 63;
  const int wv = tid >> 6;          // 0..4
  const int l15 = lane & 15;
  const int lhi = lane >> 4;
  const int rb = blockIdx.x * 64;
  const int tr = wv * 16 + l15;     // this lane's A-row (tile-local)
  const int grow = rb - 16 + tr;    // global row of A-row

  float bm1v[4], bm2v[4], bu1v[4], bu2v[4], lngv[4], lnbv[4];
#pragma unroll
  for (int ct = 0; ct < 4; ++ct) {
    int c = ct * 16 + l15;
    bm1v[ct] = bm1[c]; bm2v[ct] = bm2[c];
    bu1v[ct] = bu1[c]; bu2v[ct] = bu2[c];
    lngv[ct] = lng[c]; lnbv[ct] = lnb[c];
  }

  // ---- stage W1 <- wm1t ----
  for (int i = tid; i < 1024; i += 320) {
    int n = i >> 4, g = (i & 15) * 8;
    *reinterpret_cast<bf16x8*>(&W1[n * W1S + g]) = ld8(wm1t + n * 128 + g);
  }

  // ---- embed (owner-gather): hreg f32 + Hb bf16 tile ----
  float hreg[4][4];
#pragma unroll
  for (int r = 0; r < 4; ++r) {
    int trr = wv * 16 + lhi * 4 + r;
    int g = rb - 16 + trr;
    int gx = g < 0 ? 0 : g;
    const int* xp = x + gx * 4;
    int t0 = xp[0] * DD, t1 = xp[1] * DD, t2 = xp[2] * DD, t3 = xp[3] * DD;
#pragma unroll
    for (int ct = 0; ct < 4; ++ct) {
      int c = ct * 16 + l15;
      float s = emb[t0 + c] + emb[t1 + c] + emb[t2 + c] + emb[t3 + c];
      hreg[ct][r] = s * 0.25f;
      Hb[trr * HBS + c] = (bf16)hreg[ct][r];
    }
  }
  __syncthreads();

  f32x4 acc[4];
  const f32x4 fz = {0.f, 0.f, 0.f, 0.f};

  for (int rd = 0; rd < 3; ++rd) {
    // ======== GEMM1: [h,left] @ wm1 (W1 holds wm1t here) ========
    bf16x8 ah0 = ld8(&Hb[tr * HBS + lhi * 8]);
    bf16x8 ah1 = ld8(&Hb[tr * HBS + 32 + lhi * 8]);
    bf16x8 al0 = zero8(), al1 = zero8();
    if (tr != 0 && (grow & (NPB - 1)) != 0) {
      al0 = ld8(&Hb[(tr - 1) * HBS + lhi * 8]);
      al1 = ld8(&Hb[(tr - 1) * HBS + 32 + lhi * 8]);
    }
#pragma unroll
    for (int ct = 0; ct < 4; ++ct) acc[ct] = fz;
#pragma unroll
    for (int ct = 0; ct < 4; ++ct) {
      const bf16* wb = &W1[(ct * 16 + l15) * W1S];
      acc[ct] = mfma16(ah0, ld8(wb + lhi * 8), acc[ct]);
      acc[ct] = mfma16(ah1, ld8(wb + 32 + lhi * 8), acc[ct]);
      acc[ct] = mfma16(al0, ld8(wb + 64 + lhi * 8), acc[ct]);
      acc[ct] = mfma16(al1, ld8(wb + 96 + lhi * 8), acc[ct]);
    }
#pragma unroll
    for (int ct = 0; ct < 4; ++ct)
#pragma unroll
      for (int r = 0; r < 4; ++r) {
        float g = gelu_exact(acc[ct][r] + bm1v[ct]);
        Hs[(wv * 16 + lhi * 4 + r) * W2S + ct * 16 + l15] = (bf16)g;  // own rows
      }
    COMPILER_FENCE();

    // ======== GEMM2: g @ wm2 -> msgs -> Hb cols 64:128 ========
    {
      bf16x8 g0 = ld8(&Hs[tr * W2S + lhi * 8]);
      bf16x8 g1 = ld8(&Hs[tr * W2S + 32 + lhi * 8]);
#pragma unroll
      for (int ct = 0; ct < 4; ++ct) acc[ct] = fz;
#pragma unroll
      for (int ct = 0; ct < 4; ++ct) {
        bf16x8 f0 = ld8(wm2t + (ct * 16 + l15) * 64 + lhi * 8);
        bf16x8 f1 = ld8(wm2t + (ct * 16 + l15) * 64 + 32 + lhi * 8);
        acc[ct] = mfma16(g0, f0, acc[ct]);
        acc[ct] = mfma16(g1, f1, acc[ct]);
      }
#pragma unroll
      for (int ct = 0; ct < 4; ++ct)
#pragma unroll
        for (int r = 0; r < 4; ++r)
          Hb[(wv * 16 + lhi * 4 + r) * HBS + 64 + ct * 16 + l15] =
              (bf16)(acc[ct][r] + bm2v[ct]);
    }
    __syncthreads();                      // all GEMM1 W1-reads + msg writes done
    for (int i = tid; i < 1024; i += 320) {   // W1 <- wu1t
      int n = i >> 4, g = (i & 15) * 8;
      *reinterpret_cast<bf16x8*>(&W1[n * W1S + g]) = ld8(wu1t + n * 128 + g);
    }
    __syncthreads();

    // ======== GEMM3: [h,msgs] @ wu1 ========
    {
      bf16x8 m0 = ld8(&Hb[tr * HBS + 64 + lhi * 8]);
      bf16x8 m1 = ld8(&Hb[tr * HBS + 96 + lhi * 8]);
#pragma unroll
      for (int ct = 0; ct < 4; ++ct) acc[ct] = fz;
#pragma unroll
      for (int ct = 0; ct < 4; ++ct) {
        const bf16* wb = &W1[(ct * 16 + l15) * W1S];
        acc[ct] = mfma16(ah0, ld8(wb + lhi * 8), acc[ct]);
        acc[ct] = mfma16(ah1, ld8(wb + 32 + lhi * 8), acc[ct]);
        acc[ct] = mfma16(m0, ld8(wb + 64 + lhi * 8), acc[ct]);
        acc[ct] = mfma16(m1, ld8(wb + 96 + lhi * 8), acc[ct]);
      }
    }
#pragma unroll
    for (int ct = 0; ct < 4; ++ct)
#pragma unroll
      for (int r = 0; r < 4; ++r) {
        float g = gelu_exact(acc[ct][r] + bu1v[ct]);
        Hs[(wv * 16 + lhi * 4 + r) * W2S + ct * 16 + l15] = (bf16)g;
      }
    COMPILER_FENCE();

    // ======== GEMM4: gu @ wu2 -> upd; residual(f32 regs) + LN ========
    {
      bf16x8 u0 = ld8(&Hs[tr * W2S + lhi * 8]);
      bf16x8 u1 = ld8(&Hs[tr * W2S + 32 + lhi * 8]);
#pragma unroll
      for (int ct = 0; ct < 4; ++ct) acc[ct] = fz;
#pragma unroll
      for (int ct = 0; ct < 4; ++ct) {
        bf16x8 f0 = ld8(wu2t + (ct * 16 + l15) * 64 + lhi * 8);
        bf16x8 f1 = ld8(wu2t + (ct * 16 + l15) * 64 + 32 + lhi * 8);
        acc[ct] = mfma16(u0, f0, acc[ct]);
        acc[ct] = mfma16(u1, f1, acc[ct]);
      }
    }
    float xv[4][4];
#pragma unroll
    for (int ct = 0; ct < 4; ++ct)
#pragma unroll
      for (int r = 0; r < 4; ++r)
        xv[ct][r] = acc[ct][r] + bu2v[ct] + hreg[ct][r];
    float s1[4], s2[4];
#pragma unroll
    for (int r = 0; r < 4; ++r) {
      s1[r] = 0.f; s2[r] = 0.f;
#pragma unroll
      for (int ct = 0; ct < 4; ++ct) {
        s1[r] += xv[ct][r];
        s2[r] += xv[ct][r] * xv[ct][r];
      }
    }
#pragma unroll
    for (int off = 1; off < 16; off <<= 1)
#pragma unroll
      for (int r = 0; r < 4; ++r) {
        s1[r] += __shfl_xor(s1[r], off);
        s2[r] += __shfl_xor(s2[r], off);
      }
#pragma unroll
    for (int r = 0; r < 4; ++r) {
      float mu = s1[r] * 0.015625f;
      float var = s2[r] * 0.015625f - mu * mu;
      float rstd = rsqrtf(var + 1e-5f);
      int trr = wv * 16 + lhi * 4 + r;
#pragma unroll
      for (int ct = 0; ct < 4; ++ct) {
        float o = (xv[ct][r] - mu) * rstd * lngv[ct] + lnbv[ct];
        hreg[ct][r] = o;
        Hb[trr * HBS + ct * 16 + l15] = (bf16)o;
      }
    }
    __syncthreads();                      // h update visible (cross-wave left)
    if (rd < 2) {
      for (int i = tid; i < 1024; i += 320) {   // W1 <- wm1t for next round
        int n = i >> 4, g = (i & 15) * 8;
        *reinterpret_cast<bf16x8*>(&W1[n * W1S + g]) = ld8(wm1t + n * 128 + g);
      }
      __syncthreads();
    }
  }

  // ---------------- readout (waves 1..4; two vocab halves) ----------------
  const int node = rb + (wv - 1) * 16 + l15;  // valid when wv>=1; == grow for wv>=1
  bf16x8 b0 = ld8(&Hb[tr * HBS + lhi * 8]);   // final-h B-frags
  bf16x8 b1 = ld8(&Hb[tr * HBS + 32 + lhi * 8]);

#pragma unroll
  for (int half = 0; half < 2; ++half) {
    for (int i = tid; i < 1024; i += 320) {   // Wt <- wrt half (over Hs+W1)
      int v = i >> 3, g = (i & 7) * 8;
      *reinterpret_cast<bf16x8*>(&Wt[v * W2S + g]) =
          ld8(wrt + half * 8192 + v * 64 + g);
    }
    __syncthreads();
    if (wv >= 1) {
#pragma unroll
      for (int vt = 0; vt < 8; ++vt) {
        const bf16* wb = &Wt[(vt * 16 + l15) * W2S];
        f32x4 a = mfma16(ld8(wb + lhi * 8), b0, fz);
        a = mfma16(ld8(wb + 32 + lhi * 8), b1, a);
        f32x4 brv = *reinterpret_cast<const f32x4*>(br + half * 128 + vt * 16 + lhi * 4);
        f32x4 val = a + brv;
        float* p = out + (size_t)node * 1024 + half * 128 + vt * 16 + lhi * 4;
#pragma unroll
        for (int rep = 0; rep < 4; ++rep)
          *reinterpret_cast<f32x4*>(p + rep * 256) = val;
      }
    }
    __syncthreads();
  }
}

extern "C" void kernel_launch(void* const* d_in, const int* in_sizes, int n_in,
                              void* d_out, int out_size, void* d_ws, size_t ws_size,
                              hipStream_t stream) {
  const int*   x   = (const int*)d_in[0];
  const float* emb = (const float*)d_in[1];
  const float* wm1 = (const float*)d_in[2];
  const float* bm1 = (const float*)d_in[3];
  const float* wm2 = (const float*)d_in[4];
  const float* bm2 = (const float*)d_in[5];
  const float* wu1 = (const float*)d_in[6];
  const float* bu1 = (const float*)d_in[7];
  const float* wu2 = (const float*)d_in[8];
  const float* bu2 = (const float*)d_in[9];
  const float* lng = (const float*)d_in[10];
  const float* lnb = (const float*)d_in[11];
  const float* wr  = (const float*)d_in[12];
  const float* br  = (const float*)d_in[13];
  float* out = (float*)d_out;

  bf16* Wsc = (bf16*)d_ws;   // 80 KB of the proven 32 MB ws

  hipLaunchKernelGGL(k_prep, dim3(160), dim3(256), 0, stream,
                     wm1, wm2, wu1, wu2, wr, Wsc);
  hipLaunchKernelGGL(k_fused, dim3(1024), dim3(320), 0, stream,
                     x, emb, Wsc, bm1, bm2, bu1, bu2, lng, lnb, br, out);
}

// Round 6
// 145.930 us; speedup vs baseline: 1.0695x; 1.0695x over previous
//
#include <hip/hip_runtime.h>
#include <hip/hip_bf16.h>
#include <math.h>

#define DD 64
#define NPB 2048          // nodes per batch (N)
#define RTOT 65536        // total node rows B*N

typedef __bf16 bf16;
typedef bf16 bf16x8 __attribute__((ext_vector_type(8)));
typedef float f32x4 __attribute__((ext_vector_type(4)));

#define COMPILER_FENCE() asm volatile("" ::: "memory")

__device__ __forceinline__ f32x4 mfma16(bf16x8 a, bf16x8 b, f32x4 c) {
  return __builtin_amdgcn_mfma_f32_16x16x32_bf16(a, b, c, 0, 0, 0);
}

// Branchless exact-erf GELU: A&S 7.1.26 (|erf err| <= 1.5e-7), rcp+exp+FMA.
__device__ __forceinline__ float gelu_fast(float x) {
  float u = fabsf(x) * 0.70710678118654752f;
  float t = __builtin_amdgcn_rcpf(fmaf(0.3275911f, u, 1.0f));
  float p = t * fmaf(t, fmaf(t, fmaf(t, fmaf(t, 1.061405429f, -1.453152027f),
                                     1.421413741f), -0.284496736f), 0.254829592f);
  float e = __expf(-u * u);
  float erfa = fmaf(-p, e, 1.0f);          // erf(|x|/sqrt2)
  float s = copysignf(erfa, x);
  return 0.5f * x * (1.0f + s);
}

// XOR swizzle (16B-slot granularity): elem-index xor of bits 3..5 by row&7.
__device__ __forceinline__ int swz(int col, int row) {
  return col ^ ((row & 7) << 3);
}

// ---------------- embedding + patch mean ----------------
__global__ void __launch_bounds__(256) k_embed(const int* __restrict__ x,
                                               const float* __restrict__ emb,
                                               float* __restrict__ h) {
  int gid = blockIdx.x * 256 + threadIdx.x;
  int row = gid >> 6, d = gid & 63;
  const int* xp = x + row * 4;
  float s = 0.f;
#pragma unroll
  for (int p = 0; p < 4; ++p) s += emb[xp[p] * DD + d];
  h[row * DD + d] = s * 0.25f;
}

// ---- prep: convert+transpose round weights into d_out scratch (bf16) ----
__global__ void __launch_bounds__(256) k_prep(const float* __restrict__ wm1,
                                              const float* __restrict__ wm2,
                                              const float* __restrict__ wu1,
                                              const float* __restrict__ wu2,
                                              bf16* __restrict__ Wsc) {
  int gid = blockIdx.x * 256 + threadIdx.x;   // 96 * 256 = 24576
  if (gid < 8192) {
    int n = gid >> 7, k = gid & 127;
    Wsc[gid] = (bf16)wm1[k * 64 + n];
  } else if (gid < 16384) {
    int j = gid - 8192, n = j >> 7, k = j & 127;
    Wsc[gid] = (bf16)wu1[k * 64 + n];
  } else if (gid < 20480) {
    int j = gid - 16384, n = j >> 6, k = j & 63;
    Wsc[gid] = (bf16)wm2[k * 64 + n];
  } else {
    int j = gid - 20480, n = j >> 6, k = j & 63;
    Wsc[gid] = (bf16)wu2[k * 64 + n];
  }
}

// ---- prep readout weights: wrt[v][k] = wr[k][v], bf16, into ha (dead) ----
__global__ void __launch_bounds__(256) k_prep_r(const float* __restrict__ wr,
                                                bf16* __restrict__ wrt) {
  int gid = blockIdx.x * 256 + threadIdx.x;   // 64 * 256 = 16384
  int v = gid >> 6, k = gid & 63;
  wrt[gid] = (bf16)wr[k * 256 + v];
}

// ---------------- one message-passing round (MFMA, swizzled LDS) ----------------
__global__ void __launch_bounds__(256) k_round_m(const float* __restrict__ hin,
                                                 float* __restrict__ hout,
                                                 const bf16* __restrict__ Wsc,
                                                 const float* __restrict__ bm1,
                                                 const float* __restrict__ bm2,
                                                 const float* __restrict__ bu1,
                                                 const float* __restrict__ bu2,
                                                 const float* __restrict__ lng,
                                                 const float* __restrict__ lnb) {
  __shared__ bf16 W1[2][64 * 128];  // [0]=wm1t, [1]=wu1t, [n][k] XOR-swizzled
  __shared__ bf16 Ms[64 * 64];      // msgs (swizzled)
  __shared__ bf16 Hs[64 * 64];      // GELU intermediates (swizzled)

  const int tid = threadIdx.x;
  const int lane = tid & 63;
  const int wv = tid >> 6;
  const int l15 = lane & 15;
  const int lhi = lane >> 4;
  const int rowbase = blockIdx.x * 64;

  // ---- stage W1 (both) via vector copies, swizzled dest ----
  for (int i = tid; i < 2048; i += 256) {
    int buf = i >> 10, idx = i & 1023;
    int n = idx >> 4, g = (idx & 15) * 8;
    *reinterpret_cast<bf16x8*>(&W1[buf][n * 128 + swz(g, n)]) =
        *reinterpret_cast<const bf16x8*>(Wsc + buf * 8192 + n * 128 + g);
  }
  // ---- wm2/wu2 B-fragments in registers ----
  bf16x8 fm2[4][2], fu2[4][2];
#pragma unroll
  for (int ct = 0; ct < 4; ++ct)
#pragma unroll
    for (int kt = 0; kt < 2; ++kt) {
      int off = (ct * 16 + l15) * 64 + kt * 32 + lhi * 8;
      fm2[ct][kt] = *reinterpret_cast<const bf16x8*>(Wsc + 16384 + off);
      fu2[ct][kt] = *reinterpret_cast<const bf16x8*>(Wsc + 20480 + off);
    }
  float bm1v[4], bm2v[4], bu1v[4], bu2v[4], lngv[4], lnbv[4];
#pragma unroll
  for (int ct = 0; ct < 4; ++ct) {
    int c = ct * 16 + l15;
    bm1v[ct] = bm1[c]; bm2v[ct] = bm2[c];
    bu1v[ct] = bu1[c]; bu2v[ct] = bu2[c];
    lngv[ct] = lng[c]; lnbv[ct] = lnb[c];
  }
  __syncthreads();

  const int lrow = wv * 16 + l15;
  const int grow = rowbase + lrow;
  const float* hrow = hin + (size_t)grow * DD;

  // A-fragments of h and left, f32->bf16
  bf16x8 ah0, ah1, al0, al1;
  {
    f32x4 a = *reinterpret_cast<const f32x4*>(hrow + lhi * 8);
    f32x4 b = *reinterpret_cast<const f32x4*>(hrow + lhi * 8 + 4);
    f32x4 c = *reinterpret_cast<const f32x4*>(hrow + 32 + lhi * 8);
    f32x4 d = *reinterpret_cast<const f32x4*>(hrow + 32 + lhi * 8 + 4);
#pragma unroll
    for (int j = 0; j < 4; ++j) {
      ah0[j] = (bf16)a[j]; ah0[4 + j] = (bf16)b[j];
      ah1[j] = (bf16)c[j]; ah1[4 + j] = (bf16)d[j];
      al0[j] = (bf16)0.f; al0[4 + j] = (bf16)0.f;
      al1[j] = (bf16)0.f; al1[4 + j] = (bf16)0.f;
    }
    if ((grow & (NPB - 1)) != 0) {
      f32x4 e = *reinterpret_cast<const f32x4*>(hrow - DD + lhi * 8);
      f32x4 f = *reinterpret_cast<const f32x4*>(hrow - DD + lhi * 8 + 4);
      f32x4 g = *reinterpret_cast<const f32x4*>(hrow - DD + 32 + lhi * 8);
      f32x4 h = *reinterpret_cast<const f32x4*>(hrow - DD + 32 + lhi * 8 + 4);
#pragma unroll
      for (int j = 0; j < 4; ++j) {
        al0[j] = (bf16)e[j]; al0[4 + j] = (bf16)f[j];
        al1[j] = (bf16)g[j]; al1[4 + j] = (bf16)h[j];
      }
    }
  }

  f32x4 acc[4];
  const f32x4 fz = {0.f, 0.f, 0.f, 0.f};

  // ======== GEMM1: [h,left] @ wm1 (K=128) -> GELU -> Hs ========
#pragma unroll
  for (int ct = 0; ct < 4; ++ct) acc[ct] = fz;
#pragma unroll
  for (int ct = 0; ct < 4; ++ct) {
    const bf16* wb = &W1[0][(ct * 16 + l15) * 128];
    const int sx = (l15 & 7) << 3;
    acc[ct] = mfma16(ah0, *reinterpret_cast<const bf16x8*>(wb + ((lhi * 8) ^ sx)), acc[ct]);
    acc[ct] = mfma16(ah1, *reinterpret_cast<const bf16x8*>(wb + ((32 + lhi * 8) ^ sx)), acc[ct]);
    acc[ct] = mfma16(al0, *reinterpret_cast<const bf16x8*>(wb + ((64 + lhi * 8) ^ sx)), acc[ct]);
    acc[ct] = mfma16(al1, *reinterpret_cast<const bf16x8*>(wb + ((96 + lhi * 8) ^ sx)), acc[ct]);
  }
#pragma unroll
  for (int ct = 0; ct < 4; ++ct)
#pragma unroll
    for (int r = 0; r < 4; ++r) {
      float g = gelu_fast(acc[ct][r] + bm1v[ct]);
      int row = wv * 16 + lhi * 4 + r;
      Hs[row * 64 + swz(ct * 16 + l15, row)] = (bf16)g;   // own rows only
    }
  COMPILER_FENCE();

  // ======== GEMM2: g @ wm2 (K=64) -> msgs -> Ms ========
#pragma unroll
  for (int ct = 0; ct < 4; ++ct) acc[ct] = fz;
  {
    const int sx = (lrow & 7) << 3;
    bf16x8 g0 = *reinterpret_cast<const bf16x8*>(&Hs[lrow * 64 + ((lhi * 8) ^ sx)]);
    bf16x8 g1 = *reinterpret_cast<const bf16x8*>(&Hs[lrow * 64 + ((32 + lhi * 8) ^ sx)]);
#pragma unroll
    for (int ct = 0; ct < 4; ++ct) {
      acc[ct] = mfma16(g0, fm2[ct][0], acc[ct]);
      acc[ct] = mfma16(g1, fm2[ct][1], acc[ct]);
    }
  }
#pragma unroll
  for (int ct = 0; ct < 4; ++ct)
#pragma unroll
    for (int r = 0; r < 4; ++r) {
      int row = wv * 16 + lhi * 4 + r;
      Ms[row * 64 + swz(ct * 16 + l15, row)] = (bf16)(acc[ct][r] + bm2v[ct]);
    }
  COMPILER_FENCE();

  // ======== GEMM3: [h,msgs] @ wu1 (K=128) -> GELU -> Hs ========
#pragma unroll
  for (int ct = 0; ct < 4; ++ct) acc[ct] = fz;
  {
    const int sxm = (lrow & 7) << 3;
    bf16x8 m0 = *reinterpret_cast<const bf16x8*>(&Ms[lrow * 64 + ((lhi * 8) ^ sxm)]);
    bf16x8 m1 = *reinterpret_cast<const bf16x8*>(&Ms[lrow * 64 + ((32 + lhi * 8) ^ sxm)]);
#pragma unroll
    for (int ct = 0; ct < 4; ++ct) {
      const bf16* wb = &W1[1][(ct * 16 + l15) * 128];
      const int sx = (l15 & 7) << 3;
      acc[ct] = mfma16(ah0, *reinterpret_cast<const bf16x8*>(wb + ((lhi * 8) ^ sx)), acc[ct]);
      acc[ct] = mfma16(ah1, *reinterpret_cast<const bf16x8*>(wb + ((32 + lhi * 8) ^ sx)), acc[ct]);
      acc[ct] = mfma16(m0, *reinterpret_cast<const bf16x8*>(wb + ((64 + lhi * 8) ^ sx)), acc[ct]);
      acc[ct] = mfma16(m1, *reinterpret_cast<const bf16x8*>(wb + ((96 + lhi * 8) ^ sx)), acc[ct]);
    }
  }
  COMPILER_FENCE();
#pragma unroll
  for (int ct = 0; ct < 4; ++ct)
#pragma unroll
    for (int r = 0; r < 4; ++r) {
      float g = gelu_fast(acc[ct][r] + bu1v[ct]);
      int row = wv * 16 + lhi * 4 + r;
      Hs[row * 64 + swz(ct * 16 + l15, row)] = (bf16)g;
    }
  COMPILER_FENCE();

  // ======== GEMM4: gu @ wu2 (K=64) -> upd; residual + LN ========
#pragma unroll
  for (int ct = 0; ct < 4; ++ct) acc[ct] = fz;
  {
    const int sx = (lrow & 7) << 3;
    bf16x8 u0 = *reinterpret_cast<const bf16x8*>(&Hs[lrow * 64 + ((lhi * 8) ^ sx)]);
    bf16x8 u1 = *reinterpret_cast<const bf16x8*>(&Hs[lrow * 64 + ((32 + lhi * 8) ^ sx)]);
#pragma unroll
    for (int ct = 0; ct < 4; ++ct) {
      acc[ct] = mfma16(u0, fu2[ct][0], acc[ct]);
      acc[ct] = mfma16(u1, fu2[ct][1], acc[ct]);
    }
  }

  float xv[4][4];
#pragma unroll
  for (int ct = 0; ct < 4; ++ct)
#pragma unroll
    for (int r = 0; r < 4; ++r) {
      int row = rowbase + wv * 16 + lhi * 4 + r;
      xv[ct][r] = acc[ct][r] + bu2v[ct] + hin[row * DD + ct * 16 + l15];
    }
  float s1[4], s2[4];
#pragma unroll
  for (int r = 0; r < 4; ++r) {
    s1[r] = 0.f; s2[r] = 0.f;
#pragma unroll
    for (int ct = 0; ct < 4; ++ct) {
      s1[r] += xv[ct][r];
      s2[r] += xv[ct][r] * xv[ct][r];
    }
  }
#pragma unroll
  for (int off = 1; off < 16; off <<= 1)
#pragma unroll
    for (int r = 0; r < 4; ++r) {
      s1[r] += __shfl_xor(s1[r], off);
      s2[r] += __shfl_xor(s2[r], off);
    }
#pragma unroll
  for (int r = 0; r < 4; ++r) {
    float mu = s1[r] * 0.015625f;
    float var = s2[r] * 0.015625f - mu * mu;
    float rstd = rsqrtf(var + 1e-5f);
    int row = rowbase + wv * 16 + lhi * 4 + r;
#pragma unroll
    for (int ct = 0; ct < 4; ++ct)
      hout[row * DD + ct * 16 + l15] =
          (xv[ct][r] - mu) * rstd * lngv[ct] + lnbv[ct];
  }
}

// ---------------- readout (MFMA, swapped operands, swizzled Wt) ----------------
__global__ void __launch_bounds__(256) k_readout(const float* __restrict__ h,
                                                 const bf16* __restrict__ wrt,
                                                 const float* __restrict__ br,
                                                 float* __restrict__ out) {
  __shared__ bf16 Wt[256 * 64];  // wrt [v][k], XOR-swizzled, 32 KB
  const int tid = threadIdx.x, lane = tid & 63, wv = tid >> 6;
  const int l15 = lane & 15, lhi = lane >> 4;

  for (int i = tid; i < 2048; i += 256) {
    int v = i >> 3, g = (i & 7) * 8;
    *reinterpret_cast<bf16x8*>(&Wt[v * 64 + swz(g, v)]) =
        *reinterpret_cast<const bf16x8*>(wrt + v * 64 + g);
  }
  f32x4 brv[16];
#pragma unroll
  for (int vt = 0; vt < 16; ++vt)
    brv[vt] = *reinterpret_cast<const f32x4*>(br + vt * 16 + lhi * 4);
  __syncthreads();

  const int node = blockIdx.x * 64 + wv * 16 + l15;
  const float* hrow = h + (size_t)node * DD;
  bf16x8 b0, b1;
  {
    f32x4 a = *reinterpret_cast<const f32x4*>(hrow + lhi * 8);
    f32x4 b = *reinterpret_cast<const f32x4*>(hrow + lhi * 8 + 4);
    f32x4 c = *reinterpret_cast<const f32x4*>(hrow + 32 + lhi * 8);
    f32x4 d = *reinterpret_cast<const f32x4*>(hrow + 32 + lhi * 8 + 4);
#pragma unroll
    for (int j = 0; j < 4; ++j) {
      b0[j] = (bf16)a[j]; b0[4 + j] = (bf16)b[j];
      b1[j] = (bf16)c[j]; b1[4 + j] = (bf16)d[j];
    }
  }

  f32x4 acc[16];
  const f32x4 fz = {0.f, 0.f, 0.f, 0.f};
  const int sx = (l15 & 7) << 3;
#pragma unroll
  for (int vt = 0; vt < 16; ++vt) {
    const bf16* wb = &Wt[(vt * 16 + l15) * 64];
    bf16x8 a0 = *reinterpret_cast<const bf16x8*>(wb + ((lhi * 8) ^ sx));
    bf16x8 a1 = *reinterpret_cast<const bf16x8*>(wb + ((32 + lhi * 8) ^ sx));
    acc[vt] = mfma16(a0, b0, fz);
    acc[vt] = mfma16(a1, b1, acc[vt]);
  }

  float* ob = out + (size_t)node * 1024 + lhi * 4;
#pragma unroll
  for (int vt = 0; vt < 16; ++vt) {
    f32x4 val = acc[vt] + brv[vt];
    float* p = ob + vt * 16;
#pragma unroll
    for (int rep = 0; rep < 4; ++rep)
      *reinterpret_cast<f32x4*>(p + rep * 256) = val;
  }
}

extern "C" void kernel_launch(void* const* d_in, const int* in_sizes, int n_in,
                              void* d_out, int out_size, void* d_ws, size_t ws_size,
                              hipStream_t stream) {
  const int*   x   = (const int*)d_in[0];
  const float* emb = (const float*)d_in[1];
  const float* wm1 = (const float*)d_in[2];
  const float* bm1 = (const float*)d_in[3];
  const float* wm2 = (const float*)d_in[4];
  const float* bm2 = (const float*)d_in[5];
  const float* wu1 = (const float*)d_in[6];
  const float* bu1 = (const float*)d_in[7];
  const float* wu2 = (const float*)d_in[8];
  const float* bu2 = (const float*)d_in[9];
  const float* lng = (const float*)d_in[10];
  const float* lnb = (const float*)d_in[11];
  const float* wr  = (const float*)d_in[12];
  const float* br  = (const float*)d_in[13];
  float* out = (float*)d_out;

  char* ws = (char*)d_ws;
  float* ha = (float*)ws;                                   // 16 MB
  float* hb = (float*)(ws + (size_t)RTOT * DD * 4);         // 16 MB
  bf16* Wsc = (bf16*)d_out;      // 48 KB round-weight scratch (dead by readout)
  bf16* wrt = (bf16*)ha;         // 32 KB readout weights (ha dead after round 3)

  hipLaunchKernelGGL(k_prep, dim3(96), dim3(256), 0, stream,
                     wm1, wm2, wu1, wu2, Wsc);
  hipLaunchKernelGGL(k_embed, dim3(16384), dim3(256), 0, stream, x, emb, ha);
  hipLaunchKernelGGL(k_round_m, dim3(1024), dim3(256), 0, stream,
                     ha, hb, Wsc, bm1, bm2, bu1, bu2, lng, lnb);
  hipLaunchKernelGGL(k_round_m, dim3(1024), dim3(256), 0, stream,
                     hb, ha, Wsc, bm1, bm2, bu1, bu2, lng, lnb);
  hipLaunchKernelGGL(k_round_m, dim3(1024), dim3(256), 0, stream,
                     ha, hb, Wsc, bm1, bm2, bu1, bu2, lng, lnb);
  hipLaunchKernelGGL(k_prep_r, dim3(64), dim3(256), 0, stream, wr, wrt);
  hipLaunchKernelGGL(k_readout, dim3(1024), dim3(256), 0, stream, hb, wrt, br, out);
}

// Round 7
// 120.415 us; speedup vs baseline: 1.2961x; 1.2119x over previous
//
#include <hip/hip_runtime.h>
#include <hip/hip_bf16.h>
#include <math.h>

#define DD 64
#define NPB 2048          // nodes per batch (N)
#define RTOT 65536        // total node rows B*N

typedef __bf16 bf16;
typedef bf16 bf16x8 __attribute__((ext_vector_type(8)));
typedef float f32x4 __attribute__((ext_vector_type(4)));
typedef short short4v __attribute__((ext_vector_type(4)));

#define COMPILER_FENCE() asm volatile("" ::: "memory")

__device__ __forceinline__ f32x4 mfma16(bf16x8 a, bf16x8 b, f32x4 c) {
  return __builtin_amdgcn_mfma_f32_16x16x32_bf16(a, b, c, 0, 0, 0);
}

// Branchless exact-erf GELU: A&S 7.1.26 (|erf err| <= 1.5e-7).
__device__ __forceinline__ float gelu_fast(float x) {
  float u = fabsf(x) * 0.70710678118654752f;
  float t = __builtin_amdgcn_rcpf(fmaf(0.3275911f, u, 1.0f));
  float p = t * fmaf(t, fmaf(t, fmaf(t, fmaf(t, 1.061405429f, -1.453152027f),
                                     1.421413741f), -0.284496736f), 0.254829592f);
  float e = __expf(-u * u);
  float erfa = fmaf(-p, e, 1.0f);
  float s = copysignf(erfa, x);
  return 0.5f * x * (1.0f + s);
}

// XOR swizzle (16B-slot granularity) within a row: flips elem bits 3..5 by row&7.
__device__ __forceinline__ int swz(int col, int row) {
  return col ^ ((row & 7) << 3);
}

__device__ __forceinline__ bf16x8 ld8(const bf16* p) {
  return *reinterpret_cast<const bf16x8*>(p);
}

// ---- prep: all weights -> bf16 transposed into Wsc (ws scratch) ----
// [0:8192) wm1t[n][k], [8192:16384) wu1t, [16384:20480) wm2t[n][k],
// [20480:24576) wu2t, [24576:40960) wrt[v][k]
__global__ void __launch_bounds__(256) k_prep(const float* __restrict__ wm1,
                                              const float* __restrict__ wm2,
                                              const float* __restrict__ wu1,
                                              const float* __restrict__ wu2,
                                              const float* __restrict__ wr,
                                              bf16* __restrict__ Wsc) {
  int gid = blockIdx.x * 256 + threadIdx.x;   // 160 * 256 = 40960
  if (gid < 8192) {
    int n = gid >> 7, k = gid & 127;
    Wsc[gid] = (bf16)wm1[k * 64 + n];
  } else if (gid < 16384) {
    int j = gid - 8192, n = j >> 7, k = j & 127;
    Wsc[gid] = (bf16)wu1[k * 64 + n];
  } else if (gid < 20480) {
    int j = gid - 16384, n = j >> 6, k = j & 63;
    Wsc[gid] = (bf16)wm2[k * 64 + n];
  } else if (gid < 24576) {
    int j = gid - 20480, n = j >> 6, k = j & 63;
    Wsc[gid] = (bf16)wu2[k * 64 + n];
  } else {
    int j = gid - 24576, v = j >> 6, k = j & 63;
    Wsc[gid] = (bf16)wr[k * 256 + v];
  }
}

// ---------------- embedding + patch mean -> bf16 h0 ----------------
__global__ void __launch_bounds__(256) k_embed_b(const int* __restrict__ x,
                                                 const float* __restrict__ emb,
                                                 bf16* __restrict__ h) {
  int gid = blockIdx.x * 256 + threadIdx.x;   // RTOT*16 threads, 4 dims each
  int row = gid >> 4, d0 = (gid & 15) * 4;
  const int* xp = x + row * 4;
  f32x4 s = {0.f, 0.f, 0.f, 0.f};
#pragma unroll
  for (int p = 0; p < 4; ++p)
    s += *reinterpret_cast<const f32x4*>(emb + xp[p] * DD + d0);
  short4v o;
#pragma unroll
  for (int j = 0; j < 4; ++j) o[j] = (short)__builtin_bit_cast(unsigned short, (bf16)(s[j] * 0.25f));
  *reinterpret_cast<short4v*>(h + row * DD + d0) = o;
}

// ======== shared round body as a macro-free inline: returns xv (pre-LN) ====
// (kept inline in each kernel for clarity; code identical to R6-proven path)

// ---------------- one message-passing round (bf16 io, 2 tiles/block) --------
__global__ void __launch_bounds__(256) k_r(const bf16* __restrict__ hin,
                                           bf16* __restrict__ hout,
                                           const bf16* __restrict__ Wsc,
                                           const float* __restrict__ bm1,
                                           const float* __restrict__ bm2,
                                           const float* __restrict__ bu1,
                                           const float* __restrict__ bu2,
                                           const float* __restrict__ lng,
                                           const float* __restrict__ lnb) {
  __shared__ bf16 W1[2][64 * 128];  // wm1t/wu1t, XOR-swizzled
  __shared__ bf16 Ms[64 * 64];
  __shared__ bf16 Hs[64 * 64];

  const int tid = threadIdx.x;
  const int lane = tid & 63;
  const int wv = tid >> 6;
  const int l15 = lane & 15;
  const int lhi = lane >> 4;

  for (int i = tid; i < 2048; i += 256) {
    int buf = i >> 10, idx = i & 1023;
    int n = idx >> 4, g = (idx & 15) * 8;
    *reinterpret_cast<bf16x8*>(&W1[buf][n * 128 + swz(g, n)]) =
        ld8(Wsc + buf * 8192 + n * 128 + g);
  }
  bf16x8 fm2[4][2], fu2[4][2];
#pragma unroll
  for (int ct = 0; ct < 4; ++ct)
#pragma unroll
    for (int kt = 0; kt < 2; ++kt) {
      int off = (ct * 16 + l15) * 64 + kt * 32 + lhi * 8;
      fm2[ct][kt] = ld8(Wsc + 16384 + off);
      fu2[ct][kt] = ld8(Wsc + 20480 + off);
    }
  float bm1v[4], bm2v[4], bu1v[4], bu2v[4], lngv[4], lnbv[4];
#pragma unroll
  for (int ct = 0; ct < 4; ++ct) {
    int c = ct * 16 + l15;
    bm1v[ct] = bm1[c]; bm2v[ct] = bm2[c];
    bu1v[ct] = bu1[c]; bu2v[ct] = bu2[c];
    lngv[ct] = lng[c]; lnbv[ct] = lnb[c];
  }
  __syncthreads();

  const int lrow = wv * 16 + l15;
  const int sxr = (lrow & 7) << 3;
  const int sxw = (l15 & 7) << 3;      // swizzle key for weight rows (n=ct*16+l15)
  const f32x4 fz = {0.f, 0.f, 0.f, 0.f};

  for (int tt = 0; tt < 2; ++tt) {
    const int rowbase = (blockIdx.x * 2 + tt) * 64;
    const int grow = rowbase + lrow;
    const bf16* hrow = hin + (size_t)grow * DD;

    bf16x8 ah0 = ld8(hrow + lhi * 8);
    bf16x8 ah1 = ld8(hrow + 32 + lhi * 8);
    bf16x8 al0, al1;
#pragma unroll
    for (int j = 0; j < 8; ++j) { al0[j] = (bf16)0.f; al1[j] = (bf16)0.f; }
    if ((grow & (NPB - 1)) != 0) {
      al0 = ld8(hrow - DD + lhi * 8);
      al1 = ld8(hrow - DD + 32 + lhi * 8);
    }

    f32x4 acc[4];
    // ---- GEMM1 ----
#pragma unroll
    for (int ct = 0; ct < 4; ++ct) acc[ct] = fz;
#pragma unroll
    for (int ct = 0; ct < 4; ++ct) {
      const bf16* wb = &W1[0][(ct * 16 + l15) * 128];
      acc[ct] = mfma16(ah0, ld8(wb + ((lhi * 8) ^ sxw)), acc[ct]);
      acc[ct] = mfma16(ah1, ld8(wb + ((32 + lhi * 8) ^ sxw)), acc[ct]);
      acc[ct] = mfma16(al0, ld8(wb + ((64 + lhi * 8) ^ sxw)), acc[ct]);
      acc[ct] = mfma16(al1, ld8(wb + ((96 + lhi * 8) ^ sxw)), acc[ct]);
    }
#pragma unroll
    for (int ct = 0; ct < 4; ++ct)
#pragma unroll
      for (int r = 0; r < 4; ++r) {
        float g = gelu_fast(acc[ct][r] + bm1v[ct]);
        int row = wv * 16 + lhi * 4 + r;
        Hs[row * 64 + swz(ct * 16 + l15, row)] = (bf16)g;
      }
    COMPILER_FENCE();
    // ---- GEMM2 ----
#pragma unroll
    for (int ct = 0; ct < 4; ++ct) acc[ct] = fz;
    {
      bf16x8 g0 = ld8(&Hs[lrow * 64 + ((lhi * 8) ^ sxr)]);
      bf16x8 g1 = ld8(&Hs[lrow * 64 + ((32 + lhi * 8) ^ sxr)]);
#pragma unroll
      for (int ct = 0; ct < 4; ++ct) {
        acc[ct] = mfma16(g0, fm2[ct][0], acc[ct]);
        acc[ct] = mfma16(g1, fm2[ct][1], acc[ct]);
      }
    }
#pragma unroll
    for (int ct = 0; ct < 4; ++ct)
#pragma unroll
      for (int r = 0; r < 4; ++r) {
        int row = wv * 16 + lhi * 4 + r;
        Ms[row * 64 + swz(ct * 16 + l15, row)] = (bf16)(acc[ct][r] + bm2v[ct]);
      }
    COMPILER_FENCE();
    // ---- GEMM3 ----
#pragma unroll
    for (int ct = 0; ct < 4; ++ct) acc[ct] = fz;
    {
      bf16x8 m0 = ld8(&Ms[lrow * 64 + ((lhi * 8) ^ sxr)]);
      bf16x8 m1 = ld8(&Ms[lrow * 64 + ((32 + lhi * 8) ^ sxr)]);
#pragma unroll
      for (int ct = 0; ct < 4; ++ct) {
        const bf16* wb = &W1[1][(ct * 16 + l15) * 128];
        acc[ct] = mfma16(ah0, ld8(wb + ((lhi * 8) ^ sxw)), acc[ct]);
        acc[ct] = mfma16(ah1, ld8(wb + ((32 + lhi * 8) ^ sxw)), acc[ct]);
        acc[ct] = mfma16(m0, ld8(wb + ((64 + lhi * 8) ^ sxw)), acc[ct]);
        acc[ct] = mfma16(m1, ld8(wb + ((96 + lhi * 8) ^ sxw)), acc[ct]);
      }
    }
    COMPILER_FENCE();
#pragma unroll
    for (int ct = 0; ct < 4; ++ct)
#pragma unroll
      for (int r = 0; r < 4; ++r) {
        float g = gelu_fast(acc[ct][r] + bu1v[ct]);
        int row = wv * 16 + lhi * 4 + r;
        Hs[row * 64 + swz(ct * 16 + l15, row)] = (bf16)g;
      }
    COMPILER_FENCE();
    // ---- GEMM4 ----
#pragma unroll
    for (int ct = 0; ct < 4; ++ct) acc[ct] = fz;
    {
      bf16x8 u0 = ld8(&Hs[lrow * 64 + ((lhi * 8) ^ sxr)]);
      bf16x8 u1 = ld8(&Hs[lrow * 64 + ((32 + lhi * 8) ^ sxr)]);
#pragma unroll
      for (int ct = 0; ct < 4; ++ct) {
        acc[ct] = mfma16(u0, fu2[ct][0], acc[ct]);
        acc[ct] = mfma16(u1, fu2[ct][1], acc[ct]);
      }
    }
    // ---- residual + LN ----
    float xv[4][4];
#pragma unroll
    for (int ct = 0; ct < 4; ++ct)
#pragma unroll
      for (int r = 0; r < 4; ++r) {
        int row = rowbase + wv * 16 + lhi * 4 + r;
        xv[ct][r] = acc[ct][r] + bu2v[ct] + (float)hin[(size_t)row * DD + ct * 16 + l15];
      }
    float s1[4], s2[4];
#pragma unroll
    for (int r = 0; r < 4; ++r) {
      s1[r] = 0.f; s2[r] = 0.f;
#pragma unroll
      for (int ct = 0; ct < 4; ++ct) { s1[r] += xv[ct][r]; s2[r] += xv[ct][r] * xv[ct][r]; }
    }
#pragma unroll
    for (int off = 1; off < 16; off <<= 1)
#pragma unroll
      for (int r = 0; r < 4; ++r) {
        s1[r] += __shfl_xor(s1[r], off);
        s2[r] += __shfl_xor(s2[r], off);
      }
#pragma unroll
    for (int r = 0; r < 4; ++r) {
      float mu = s1[r] * 0.015625f;
      float var = s2[r] * 0.015625f - mu * mu;
      float rstd = rsqrtf(var + 1e-5f);
      int row = rowbase + wv * 16 + lhi * 4 + r;
#pragma unroll
      for (int ct = 0; ct < 4; ++ct)
        hout[(size_t)row * DD + ct * 16 + l15] =
            (bf16)((xv[ct][r] - mu) * rstd * lngv[ct] + lnbv[ct]);
    }
  }
}

// ------------- round 3 + fused readout (writes logits only) -------------
__global__ void __launch_bounds__(256) k_r3r(const bf16* __restrict__ hin,
                                             const bf16* __restrict__ Wsc,
                                             const float* __restrict__ bm1,
                                             const float* __restrict__ bm2,
                                             const float* __restrict__ bu1,
                                             const float* __restrict__ bu2,
                                             const float* __restrict__ lng,
                                             const float* __restrict__ lnb,
                                             const float* __restrict__ br,
                                             float* __restrict__ out) {
  __shared__ bf16 W1[2][64 * 128];
  __shared__ bf16 Ms[64 * 64];      // msgs, then reused for h3
  __shared__ bf16 Hs[64 * 64];

  const int tid = threadIdx.x;
  const int lane = tid & 63;
  const int wv = tid >> 6;
  const int l15 = lane & 15;
  const int lhi = lane >> 4;

  for (int i = tid; i < 2048; i += 256) {
    int buf = i >> 10, idx = i & 1023;
    int n = idx >> 4, g = (idx & 15) * 8;
    *reinterpret_cast<bf16x8*>(&W1[buf][n * 128 + swz(g, n)]) =
        ld8(Wsc + buf * 8192 + n * 128 + g);
  }
  bf16x8 fm2[4][2], fu2[4][2];
#pragma unroll
  for (int ct = 0; ct < 4; ++ct)
#pragma unroll
    for (int kt = 0; kt < 2; ++kt) {
      int off = (ct * 16 + l15) * 64 + kt * 32 + lhi * 8;
      fm2[ct][kt] = ld8(Wsc + 16384 + off);
      fu2[ct][kt] = ld8(Wsc + 20480 + off);
    }
  const bf16* wrt = Wsc + 24576;
  float bm1v[4], bm2v[4], bu1v[4], bu2v[4], lngv[4], lnbv[4];
#pragma unroll
  for (int ct = 0; ct < 4; ++ct) {
    int c = ct * 16 + l15;
    bm1v[ct] = bm1[c]; bm2v[ct] = bm2[c];
    bu1v[ct] = bu1[c]; bu2v[ct] = bu2[c];
    lngv[ct] = lng[c]; lnbv[ct] = lnb[c];
  }
  __syncthreads();

  const int lrow = wv * 16 + l15;
  const int sxr = (lrow & 7) << 3;
  const int sxw = (l15 & 7) << 3;
  const f32x4 fz = {0.f, 0.f, 0.f, 0.f};

  for (int tt = 0; tt < 2; ++tt) {
    const int rowbase = (blockIdx.x * 2 + tt) * 64;
    const int grow = rowbase + lrow;
    const bf16* hrow = hin + (size_t)grow * DD;

    bf16x8 ah0 = ld8(hrow + lhi * 8);
    bf16x8 ah1 = ld8(hrow + 32 + lhi * 8);
    bf16x8 al0, al1;
#pragma unroll
    for (int j = 0; j < 8; ++j) { al0[j] = (bf16)0.f; al1[j] = (bf16)0.f; }
    if ((grow & (NPB - 1)) != 0) {
      al0 = ld8(hrow - DD + lhi * 8);
      al1 = ld8(hrow - DD + 32 + lhi * 8);
    }

    f32x4 acc[4];
#pragma unroll
    for (int ct = 0; ct < 4; ++ct) acc[ct] = fz;
#pragma unroll
    for (int ct = 0; ct < 4; ++ct) {
      const bf16* wb = &W1[0][(ct * 16 + l15) * 128];
      acc[ct] = mfma16(ah0, ld8(wb + ((lhi * 8) ^ sxw)), acc[ct]);
      acc[ct] = mfma16(ah1, ld8(wb + ((32 + lhi * 8) ^ sxw)), acc[ct]);
      acc[ct] = mfma16(al0, ld8(wb + ((64 + lhi * 8) ^ sxw)), acc[ct]);
      acc[ct] = mfma16(al1, ld8(wb + ((96 + lhi * 8) ^ sxw)), acc[ct]);
    }
#pragma unroll
    for (int ct = 0; ct < 4; ++ct)
#pragma unroll
      for (int r = 0; r < 4; ++r) {
        float g = gelu_fast(acc[ct][r] + bm1v[ct]);
        int row = wv * 16 + lhi * 4 + r;
        Hs[row * 64 + swz(ct * 16 + l15, row)] = (bf16)g;
      }
    COMPILER_FENCE();
#pragma unroll
    for (int ct = 0; ct < 4; ++ct) acc[ct] = fz;
    {
      bf16x8 g0 = ld8(&Hs[lrow * 64 + ((lhi * 8) ^ sxr)]);
      bf16x8 g1 = ld8(&Hs[lrow * 64 + ((32 + lhi * 8) ^ sxr)]);
#pragma unroll
      for (int ct = 0; ct < 4; ++ct) {
        acc[ct] = mfma16(g0, fm2[ct][0], acc[ct]);
        acc[ct] = mfma16(g1, fm2[ct][1], acc[ct]);
      }
    }
#pragma unroll
    for (int ct = 0; ct < 4; ++ct)
#pragma unroll
      for (int r = 0; r < 4; ++r) {
        int row = wv * 16 + lhi * 4 + r;
        Ms[row * 64 + swz(ct * 16 + l15, row)] = (bf16)(acc[ct][r] + bm2v[ct]);
      }
    COMPILER_FENCE();
#pragma unroll
    for (int ct = 0; ct < 4; ++ct) acc[ct] = fz;
    {
      bf16x8 m0 = ld8(&Ms[lrow * 64 + ((lhi * 8) ^ sxr)]);
      bf16x8 m1 = ld8(&Ms[lrow * 64 + ((32 + lhi * 8) ^ sxr)]);
#pragma unroll
      for (int ct = 0; ct < 4; ++ct) {
        const bf16* wb = &W1[1][(ct * 16 + l15) * 128];
        acc[ct] = mfma16(ah0, ld8(wb + ((lhi * 8) ^ sxw)), acc[ct]);
        acc[ct] = mfma16(ah1, ld8(wb + ((32 + lhi * 8) ^ sxw)), acc[ct]);
        acc[ct] = mfma16(m0, ld8(wb + ((64 + lhi * 8) ^ sxw)), acc[ct]);
        acc[ct] = mfma16(m1, ld8(wb + ((96 + lhi * 8) ^ sxw)), acc[ct]);
      }
    }
    COMPILER_FENCE();
#pragma unroll
    for (int ct = 0; ct < 4; ++ct)
#pragma unroll
      for (int r = 0; r < 4; ++r) {
        float g = gelu_fast(acc[ct][r] + bu1v[ct]);
        int row = wv * 16 + lhi * 4 + r;
        Hs[row * 64 + swz(ct * 16 + l15, row)] = (bf16)g;
      }
    COMPILER_FENCE();
#pragma unroll
    for (int ct = 0; ct < 4; ++ct) acc[ct] = fz;
    {
      bf16x8 u0 = ld8(&Hs[lrow * 64 + ((lhi * 8) ^ sxr)]);
      bf16x8 u1 = ld8(&Hs[lrow * 64 + ((32 + lhi * 8) ^ sxr)]);
#pragma unroll
      for (int ct = 0; ct < 4; ++ct) {
        acc[ct] = mfma16(u0, fu2[ct][0], acc[ct]);
        acc[ct] = mfma16(u1, fu2[ct][1], acc[ct]);
      }
    }
    // ---- residual + LN; h3 -> Ms (own rows; Ms dead after GEMM3) ----
    float xv[4][4];
#pragma unroll
    for (int ct = 0; ct < 4; ++ct)
#pragma unroll
      for (int r = 0; r < 4; ++r) {
        int row = rowbase + wv * 16 + lhi * 4 + r;
        xv[ct][r] = acc[ct][r] + bu2v[ct] + (float)hin[(size_t)row * DD + ct * 16 + l15];
      }
    float s1[4], s2[4];
#pragma unroll
    for (int r = 0; r < 4; ++r) {
      s1[r] = 0.f; s2[r] = 0.f;
#pragma unroll
      for (int ct = 0; ct < 4; ++ct) { s1[r] += xv[ct][r]; s2[r] += xv[ct][r] * xv[ct][r]; }
    }
#pragma unroll
    for (int off = 1; off < 16; off <<= 1)
#pragma unroll
      for (int r = 0; r < 4; ++r) {
        s1[r] += __shfl_xor(s1[r], off);
        s2[r] += __shfl_xor(s2[r], off);
      }
#pragma unroll
    for (int r = 0; r < 4; ++r) {
      float mu = s1[r] * 0.015625f;
      float var = s2[r] * 0.015625f - mu * mu;
      float rstd = rsqrtf(var + 1e-5f);
      int row = wv * 16 + lhi * 4 + r;
#pragma unroll
      for (int ct = 0; ct < 4; ++ct)
        Ms[row * 64 + swz(ct * 16 + l15, row)] =
            (bf16)((xv[ct][r] - mu) * rstd * lngv[ct] + lnbv[ct]);
    }
    COMPILER_FENCE();

    // ---- fused readout: B-frags from Ms (own rows), A-frags from global wrt ----
    {
      bf16x8 b0 = ld8(&Ms[lrow * 64 + ((lhi * 8) ^ sxr)]);
      bf16x8 b1 = ld8(&Ms[lrow * 64 + ((32 + lhi * 8) ^ sxr)]);
      const int node = rowbase + lrow;
      float* ob = out + (size_t)node * 1024 + lhi * 4;
#pragma unroll
      for (int vt = 0; vt < 16; ++vt) {
        const bf16* wb = wrt + (vt * 16 + l15) * 64;
        f32x4 a = mfma16(ld8(wb + lhi * 8), b0, fz);
        a = mfma16(ld8(wb + 32 + lhi * 8), b1, a);
        f32x4 val = a + *reinterpret_cast<const f32x4*>(br + vt * 16 + lhi * 4);
        float* p = ob + vt * 16;
#pragma unroll
        for (int rep = 0; rep < 4; ++rep)
          *reinterpret_cast<f32x4*>(p + rep * 256) = val;
      }
    }
    COMPILER_FENCE();   // Ms reads done before next tile overwrites (same wave)
  }
}

extern "C" void kernel_launch(void* const* d_in, const int* in_sizes, int n_in,
                              void* d_out, int out_size, void* d_ws, size_t ws_size,
                              hipStream_t stream) {
  const int*   x   = (const int*)d_in[0];
  const float* emb = (const float*)d_in[1];
  const float* wm1 = (const float*)d_in[2];
  const float* bm1 = (const float*)d_in[3];
  const float* wm2 = (const float*)d_in[4];
  const float* bm2 = (const float*)d_in[5];
  const float* wu1 = (const float*)d_in[6];
  const float* bu1 = (const float*)d_in[7];
  const float* wu2 = (const float*)d_in[8];
  const float* bu2 = (const float*)d_in[9];
  const float* lng = (const float*)d_in[10];
  const float* lnb = (const float*)d_in[11];
  const float* wr  = (const float*)d_in[12];
  const float* br  = (const float*)d_in[13];
  float* out = (float*)d_out;

  char* ws = (char*)d_ws;
  bf16* hA  = (bf16*)ws;                                    // 8 MB
  bf16* hB  = (bf16*)(ws + (size_t)RTOT * DD * 2);          // 8 MB
  bf16* Wsc = (bf16*)(ws + (size_t)RTOT * DD * 4);          // 80 KB @ +16MB

  hipLaunchKernelGGL(k_prep, dim3(160), dim3(256), 0, stream,
                     wm1, wm2, wu1, wu2, wr, Wsc);
  hipLaunchKernelGGL(k_embed_b, dim3(4096), dim3(256), 0, stream, x, emb, hA);
  hipLaunchKernelGGL(k_r, dim3(512), dim3(256), 0, stream,
                     hA, hB, Wsc, bm1, bm2, bu1, bu2, lng, lnb);
  hipLaunchKernelGGL(k_r, dim3(512), dim3(256), 0, stream,
                     hB, hA, Wsc, bm1, bm2, bu1, bu2, lng, lnb);
  hipLaunchKernelGGL(k_r3r, dim3(512), dim3(256), 0, stream,
                     hA, Wsc, bm1, bm2, bu1, bu2, lng, lnb, br, out);
}